// Round 1
// baseline (639.349 us; speedup 1.0000x reference)
//
#include <hip/hip_runtime.h>

#define DIN 256
#define DH  128
#define DOUT 64

// ---------- CSR construction ----------

__global__ __launch_bounds__(256) void count_edges(const int* __restrict__ dst,
                                                   int* __restrict__ cnt, int E) {
  int e = blockIdx.x * 256 + threadIdx.x;
  if (e < E) atomicAdd(&cnt[dst[e]], 1);
}

__global__ __launch_bounds__(256) void reduce_chunks(const int* __restrict__ cnt,
                                                     int* __restrict__ partial, int n) {
  int t = threadIdx.x;
  int g = blockIdx.x * 256 + t;
  int v = (g < n) ? cnt[g] : 0;
  #pragma unroll
  for (int o = 32; o > 0; o >>= 1) v += __shfl_down(v, o, 64);
  __shared__ int sm[4];
  if ((t & 63) == 0) sm[t >> 6] = v;
  __syncthreads();
  if (t == 0) partial[blockIdx.x] = sm[0] + sm[1] + sm[2] + sm[3];
}

__global__ void scan_seq(int* partial, int* rowptr, int nb, int n) {
  // single thread; nb ~ 196 iterations
  int run = 0;
  for (int i = 0; i < nb; ++i) { int v = partial[i]; partial[i] = run; run += v; }
  rowptr[n] = run;
}

__global__ __launch_bounds__(256) void scan_chunks(const int* __restrict__ cnt,
    const int* __restrict__ chunkoff, int* __restrict__ rowptr, int n) {
  __shared__ int sm[256];
  int t = threadIdx.x, g = blockIdx.x * 256 + t;
  int v = (g < n) ? cnt[g] : 0;
  sm[t] = v;
  __syncthreads();
  for (int d = 1; d < 256; d <<= 1) {
    int add = (t >= d) ? sm[t - d] : 0;
    __syncthreads();
    sm[t] += add;
    __syncthreads();
  }
  if (g < n) rowptr[g] = sm[t] - v + chunkoff[blockIdx.x];
}

__global__ __launch_bounds__(256) void dinv_kernel(const int* __restrict__ cnt,
                                                   float* __restrict__ dinv, int n) {
  int i = blockIdx.x * 256 + threadIdx.x;
  if (i < n) dinv[i] = rsqrtf((float)(cnt[i] + 1));  // +1 self-loop
}

__global__ __launch_bounds__(256) void fill_csr(const int* __restrict__ src,
    const int* __restrict__ dst, const int* __restrict__ rowptr,
    int* __restrict__ cursor, int* __restrict__ csr, int E) {
  int e = blockIdx.x * 256 + threadIdx.x;
  if (e < E) {
    int d = dst[e];
    int p = rowptr[d] + atomicAdd(&cursor[d], 1);
    csr[p] = src[e];
  }
}

// ---------- dense transform (fp32, LDS-tiled) ----------
// BM=64, BK=16, BN = full output width (128 or 64), 256 threads,
// each thread: 8 rows x TN cols accumulators.

template<int BN, int TN>
__global__ __launch_bounds__(256) void gemm_tile(const float* __restrict__ A,
    const float* __restrict__ W, float* __restrict__ C, int M, int K) {
  const int tid = threadIdx.x;
  const int tx = tid & 31;   // col group: cols tx*TN .. tx*TN+TN-1
  const int ty = tid >> 5;   // row group: rows ty*8 .. ty*8+7
  const int rowBase = blockIdx.x * 64;
  __shared__ float xs[64][16];
  __shared__ float wsm[16][BN];
  float acc[8][TN];
  #pragma unroll
  for (int r = 0; r < 8; ++r)
    #pragma unroll
    for (int j = 0; j < TN; ++j) acc[r][j] = 0.f;

  for (int kt = 0; kt < K; kt += 16) {
    {
      int r = tid >> 2, kq = tid & 3;
      int grow = rowBase + r;
      float4 v = make_float4(0.f, 0.f, 0.f, 0.f);
      if (grow < M) v = *(const float4*)&A[(size_t)grow * K + kt + kq * 4];
      *(float4*)&xs[r][kq * 4] = v;
    }
    #pragma unroll
    for (int i = 0; i < BN / 64; ++i) {
      int idx = (tid + i * 256) * 4;
      int kk = idx / BN, c = idx % BN;
      *(float4*)&wsm[kk][c] = *(const float4*)&W[(size_t)(kt + kk) * BN + c];
    }
    __syncthreads();
    #pragma unroll
    for (int kk = 0; kk < 16; ++kk) {
      float a[8];
      #pragma unroll
      for (int r = 0; r < 8; ++r) a[r] = xs[ty * 8 + r][kk];
      float b[TN];
      if (TN == 4) {
        float4 bv = *(float4*)&wsm[kk][tx * 4];
        b[0] = bv.x; b[1] = bv.y; b[2] = bv.z; b[3] = bv.w;
      } else {
        float2 bv = *(float2*)&wsm[kk][tx * 2];
        b[0] = bv.x; b[1] = bv.y;
      }
      #pragma unroll
      for (int r = 0; r < 8; ++r)
        #pragma unroll
        for (int j = 0; j < TN; ++j) acc[r][j] = fmaf(a[r], b[j], acc[r][j]);
    }
    __syncthreads();
  }
  #pragma unroll
  for (int r = 0; r < 8; ++r) {
    int row = rowBase + ty * 8 + r;
    if (row < M) {
      if (TN == 4) {
        float4 v = make_float4(acc[r][0], acc[r][1], acc[r][2], acc[r][3]);
        *(float4*)&C[(size_t)row * BN + tx * 4] = v;
      } else {
        float2 v = make_float2(acc[r][0], acc[r][1]);
        *(float2*)&C[(size_t)row * BN + tx * 2] = v;
      }
    }
  }
}

// ---------- pull aggregation: one wave per node, registers accumulate ----------

// D=128: each lane owns 2 features (float2), + bias + relu
__global__ __launch_bounds__(256) void aggregate1(const float* __restrict__ h,
    const int* __restrict__ rowptr, const int* __restrict__ csr,
    const float* __restrict__ dinv, const float* __restrict__ bias,
    float* __restrict__ out, int n) {
  int wave = threadIdx.x >> 6, lane = threadIdx.x & 63;
  int node = blockIdx.x * 4 + wave;
  if (node >= n) return;
  float di = dinv[node];
  int c0 = lane * 2;
  float2 v = *(const float2*)&h[(size_t)node * DH + c0];
  float w0 = di * di;                       // self-loop norm
  float ax = v.x * w0, ay = v.y * w0;
  int p = rowptr[node], pe = rowptr[node + 1];
  for (; p < pe; ++p) {
    int s = csr[p];
    float w = dinv[s] * di;
    float2 u = *(const float2*)&h[(size_t)s * DH + c0];
    ax = fmaf(u.x, w, ax);
    ay = fmaf(u.y, w, ay);
  }
  ax += bias[c0]; ay += bias[c0 + 1];
  ax = fmaxf(ax, 0.f); ay = fmaxf(ay, 0.f);
  *(float2*)&out[(size_t)node * DH + c0] = make_float2(ax, ay);
}

// D=64: each lane owns 1 feature, + bias, no relu
__global__ __launch_bounds__(256) void aggregate2(const float* __restrict__ h,
    const int* __restrict__ rowptr, const int* __restrict__ csr,
    const float* __restrict__ dinv, const float* __restrict__ bias,
    float* __restrict__ out, int n) {
  int wave = threadIdx.x >> 6, lane = threadIdx.x & 63;
  int node = blockIdx.x * 4 + wave;
  if (node >= n) return;
  float di = dinv[node];
  float a = h[(size_t)node * DOUT + lane] * (di * di);
  int p = rowptr[node], pe = rowptr[node + 1];
  for (; p < pe; ++p) {
    int s = csr[p];
    float w = dinv[s] * di;
    a = fmaf(h[(size_t)s * DOUT + lane], w, a);
  }
  a += bias[lane];
  out[(size_t)node * DOUT + lane] = a;
}

// ---------- launch ----------

extern "C" void kernel_launch(void* const* d_in, const int* in_sizes, int n_in,
                              void* d_out, int out_size, void* d_ws, size_t ws_size,
                              hipStream_t stream) {
  const float* x  = (const float*)d_in[0];
  const int*   ei = (const int*)d_in[1];
  const float* W1 = (const float*)d_in[2];
  const float* b1 = (const float*)d_in[3];
  const float* W2 = (const float*)d_in[4];
  const float* b2 = (const float*)d_in[5];
  float* out = (float*)d_out;

  const int N = in_sizes[0] / DIN;   // 50000
  const int E = in_sizes[1] / 2;     // 1600000
  const int* src = ei;
  const int* dst = ei + E;
  const int NB = (N + 255) / 256;

  char* ws = (char*)d_ws;
  size_t o = 0;
  auto alloc = [&](size_t bytes) { size_t r = o; o += (bytes + 511) & ~(size_t)511; return r; };
  size_t cnt_o     = alloc((size_t)N * 4);
  size_t cur_o     = alloc((size_t)N * 4);
  size_t rowptr_o  = alloc((size_t)(N + 1) * 4);
  size_t partial_o = alloc((size_t)NB * 4);
  size_t dinv_o    = alloc((size_t)N * 4);
  size_t csr_o     = alloc((size_t)E * 4);
  size_t h1_o      = alloc((size_t)N * DH * 4);
  size_t g1_o      = alloc((size_t)N * DH * 4);
  size_t h2_o      = h1_o;  // h1 is dead after aggregate1 -> reuse for h2

  int*   cnt     = (int*)(ws + cnt_o);
  int*   cursor  = (int*)(ws + cur_o);
  int*   rowptr  = (int*)(ws + rowptr_o);
  int*   partial = (int*)(ws + partial_o);
  float* dinv    = (float*)(ws + dinv_o);
  int*   csr     = (int*)(ws + csr_o);
  float* h1      = (float*)(ws + h1_o);
  float* g1      = (float*)(ws + g1_o);
  float* h2      = (float*)(ws + h2_o);

  // zero cnt + cursor (contiguous region)
  hipMemsetAsync(ws + cnt_o, 0, cur_o + (size_t)N * 4 - cnt_o, stream);

  int egrid = (E + 255) / 256;
  count_edges<<<egrid, 256, 0, stream>>>(dst, cnt, E);
  reduce_chunks<<<NB, 256, 0, stream>>>(cnt, partial, N);
  scan_seq<<<1, 1, 0, stream>>>(partial, rowptr, NB, N);
  scan_chunks<<<NB, 256, 0, stream>>>(cnt, partial, rowptr, N);
  dinv_kernel<<<NB, 256, 0, stream>>>(cnt, dinv, N);
  fill_csr<<<egrid, 256, 0, stream>>>(src, dst, rowptr, cursor, csr, E);

  gemm_tile<DH, 4><<<(N + 63) / 64, 256, 0, stream>>>(x, W1, h1, N, DIN);
  aggregate1<<<(N + 3) / 4, 256, 0, stream>>>(h1, rowptr, csr, dinv, b1, g1, N);
  gemm_tile<DOUT, 2><<<(N + 63) / 64, 256, 0, stream>>>(g1, W2, h2, N, DH);
  aggregate2<<<(N + 3) / 4, 256, 0, stream>>>(h2, rowptr, csr, dinv, b2, out, N);
}

// Round 2
// 473.175 us; speedup vs baseline: 1.3512x; 1.3512x over previous
//
#include <hip/hip_runtime.h>

#define DIN 256
#define DH  128
#define DOUT 64

// ---------- CSR construction ----------

__global__ __launch_bounds__(256) void count_edges(const int* __restrict__ dst,
                                                   int* __restrict__ cnt, int E) {
  int e = blockIdx.x * 256 + threadIdx.x;
  if (e < E) atomicAdd(&cnt[dst[e]], 1);
}

__global__ __launch_bounds__(256) void reduce_chunks(const int* __restrict__ cnt,
                                                     int* __restrict__ partial, int n) {
  int t = threadIdx.x;
  int g = blockIdx.x * 256 + t;
  int v = (g < n) ? cnt[g] : 0;
  #pragma unroll
  for (int o = 32; o > 0; o >>= 1) v += __shfl_down(v, o, 64);
  __shared__ int sm[4];
  if ((t & 63) == 0) sm[t >> 6] = v;
  __syncthreads();
  if (t == 0) partial[blockIdx.x] = sm[0] + sm[1] + sm[2] + sm[3];
}

// one-block parallel scan over the NB chunk totals (replaces 1-thread serial scan)
__global__ __launch_bounds__(256) void scan_block(int* partial, int* rowptr, int nb, int n) {
  __shared__ int sm[256];
  __shared__ int carry;
  int t = threadIdx.x;
  if (t == 0) carry = 0;
  __syncthreads();
  for (int base = 0; base < nb; base += 256) {
    int g = base + t;
    int v = (g < nb) ? partial[g] : 0;
    sm[t] = v;
    __syncthreads();
    for (int d = 1; d < 256; d <<= 1) {
      int add = (t >= d) ? sm[t - d] : 0;
      __syncthreads();
      sm[t] += add;
      __syncthreads();
    }
    int excl = sm[t] - v + carry;           // exclusive prefix with carry-in
    if (g < nb) partial[g] = excl;
    __syncthreads();
    if (t == 255) carry = excl + v;         // carry-out = inclusive total
    __syncthreads();
  }
  if (t == 0) rowptr[n] = carry;
}

__global__ __launch_bounds__(256) void scan_chunks(const int* __restrict__ cnt,
    const int* __restrict__ chunkoff, int* __restrict__ rowptr,
    float* __restrict__ dinv, int n) {
  __shared__ int sm[256];
  int t = threadIdx.x, g = blockIdx.x * 256 + t;
  int v = (g < n) ? cnt[g] : 0;
  sm[t] = v;
  __syncthreads();
  for (int d = 1; d < 256; d <<= 1) {
    int add = (t >= d) ? sm[t - d] : 0;
    __syncthreads();
    sm[t] += add;
    __syncthreads();
  }
  if (g < n) {
    rowptr[g] = sm[t] - v + chunkoff[blockIdx.x];
    dinv[g] = rsqrtf((float)(v + 1));       // +1 self-loop
  }
}

__global__ __launch_bounds__(256) void fill_csr(const int* __restrict__ src,
    const int* __restrict__ dst, const int* __restrict__ rowptr,
    int* __restrict__ cursor, int* __restrict__ csr, int E) {
  int e = blockIdx.x * 256 + threadIdx.x;
  if (e < E) {
    int d = dst[e];
    int p = rowptr[d] + atomicAdd(&cursor[d], 1);
    csr[p] = src[e];
  }
}

// ---------- dense transform (fp32, LDS-tiled), epilogue scales row by dinv ----------

template<int BN, int TN>
__global__ __launch_bounds__(256) void gemm_tile(const float* __restrict__ A,
    const float* __restrict__ W, const float* __restrict__ dinv,
    float* __restrict__ C, int M, int K) {
  const int tid = threadIdx.x;
  const int tx = tid & 31;
  const int ty = tid >> 5;
  const int rowBase = blockIdx.x * 64;
  __shared__ float xs[64][16];
  __shared__ float wsm[16][BN];
  float acc[8][TN];
  #pragma unroll
  for (int r = 0; r < 8; ++r)
    #pragma unroll
    for (int j = 0; j < TN; ++j) acc[r][j] = 0.f;

  for (int kt = 0; kt < K; kt += 16) {
    {
      int r = tid >> 2, kq = tid & 3;
      int grow = rowBase + r;
      float4 v = make_float4(0.f, 0.f, 0.f, 0.f);
      if (grow < M) v = *(const float4*)&A[(size_t)grow * K + kt + kq * 4];
      *(float4*)&xs[r][kq * 4] = v;
    }
    #pragma unroll
    for (int i = 0; i < BN / 64; ++i) {
      int idx = (tid + i * 256) * 4;
      int kk = idx / BN, c = idx % BN;
      *(float4*)&wsm[kk][c] = *(const float4*)&W[(size_t)(kt + kk) * BN + c];
    }
    __syncthreads();
    #pragma unroll
    for (int kk = 0; kk < 16; ++kk) {
      float a[8];
      #pragma unroll
      for (int r = 0; r < 8; ++r) a[r] = xs[ty * 8 + r][kk];
      float b[TN];
      if (TN == 4) {
        float4 bv = *(float4*)&wsm[kk][tx * 4];
        b[0] = bv.x; b[1] = bv.y; b[2] = bv.z; b[3] = bv.w;
      } else {
        float2 bv = *(float2*)&wsm[kk][tx * 2];
        b[0] = bv.x; b[1] = bv.y;
      }
      #pragma unroll
      for (int r = 0; r < 8; ++r)
        #pragma unroll
        for (int j = 0; j < TN; ++j) acc[r][j] = fmaf(a[r], b[j], acc[r][j]);
    }
    __syncthreads();
  }
  #pragma unroll
  for (int r = 0; r < 8; ++r) {
    int row = rowBase + ty * 8 + r;
    if (row < M) {
      float s = dinv[row];                   // pre-scale: h'[i] = dinv[i] * (A@W)[i]
      if (TN == 4) {
        float4 v = make_float4(acc[r][0] * s, acc[r][1] * s, acc[r][2] * s, acc[r][3] * s);
        *(float4*)&C[(size_t)row * BN + tx * 4] = v;
      } else {
        float2 v = make_float2(acc[r][0] * s, acc[r][1] * s);
        *(float2*)&C[(size_t)row * BN + tx * 2] = v;
      }
    }
  }
}

// ---------- pull aggregation: one wave per node, 8-deep gather pipeline ----------
// h is pre-scaled by dinv[src]; per edge body = index load + row load + add.
// out = relu(di * sum + bias)  [layer 1];  out = di * sum + bias  [layer 2]

__global__ __launch_bounds__(256) void aggregate1(const float* __restrict__ h,
    const int* __restrict__ rowptr, const int* __restrict__ csr,
    const float* __restrict__ dinv, const float* __restrict__ bias,
    float* __restrict__ out, int n) {
  int lane = threadIdx.x & 63;
  int node = blockIdx.x * 4 + (threadIdx.x >> 6);
  if (node >= n) return;
  node = __builtin_amdgcn_readfirstlane(node);
  float di = dinv[node];
  int c0 = lane * 2;
  float2 v = *(const float2*)&h[(size_t)node * DH + c0];  // self-loop term (pre-scaled)
  float ax = v.x, ay = v.y;
  int p = rowptr[node], pe = rowptr[node + 1];
  for (; p + 8 <= pe; p += 8) {
    int s[8];
    #pragma unroll
    for (int j = 0; j < 8; ++j) s[j] = csr[p + j];
    #pragma unroll
    for (int j = 0; j < 8; ++j) {
      float2 u = *(const float2*)&h[(size_t)s[j] * DH + c0];
      ax += u.x; ay += u.y;
    }
  }
  for (; p < pe; ++p) {
    float2 u = *(const float2*)&h[(size_t)csr[p] * DH + c0];
    ax += u.x; ay += u.y;
  }
  ax = fmaxf(fmaf(ax, di, bias[c0]), 0.f);
  ay = fmaxf(fmaf(ay, di, bias[c0 + 1]), 0.f);
  *(float2*)&out[(size_t)node * DH + c0] = make_float2(ax, ay);
}

__global__ __launch_bounds__(256) void aggregate2(const float* __restrict__ h,
    const int* __restrict__ rowptr, const int* __restrict__ csr,
    const float* __restrict__ dinv, const float* __restrict__ bias,
    float* __restrict__ out, int n) {
  int lane = threadIdx.x & 63;
  int node = blockIdx.x * 4 + (threadIdx.x >> 6);
  if (node >= n) return;
  node = __builtin_amdgcn_readfirstlane(node);
  float di = dinv[node];
  float a = h[(size_t)node * DOUT + lane];
  int p = rowptr[node], pe = rowptr[node + 1];
  for (; p + 8 <= pe; p += 8) {
    int s[8];
    #pragma unroll
    for (int j = 0; j < 8; ++j) s[j] = csr[p + j];
    #pragma unroll
    for (int j = 0; j < 8; ++j) a += h[(size_t)s[j] * DOUT + lane];
  }
  for (; p < pe; ++p) a += h[(size_t)csr[p] * DOUT + lane];
  out[(size_t)node * DOUT + lane] = fmaf(a, di, bias[lane]);
}

// ---------- launch ----------

extern "C" void kernel_launch(void* const* d_in, const int* in_sizes, int n_in,
                              void* d_out, int out_size, void* d_ws, size_t ws_size,
                              hipStream_t stream) {
  const float* x  = (const float*)d_in[0];
  const int*   ei = (const int*)d_in[1];
  const float* W1 = (const float*)d_in[2];
  const float* b1 = (const float*)d_in[3];
  const float* W2 = (const float*)d_in[4];
  const float* b2 = (const float*)d_in[5];
  float* out = (float*)d_out;

  const int N = in_sizes[0] / DIN;   // 50000
  const int E = in_sizes[1] / 2;     // 1600000
  const int* src = ei;
  const int* dst = ei + E;
  const int NB = (N + 255) / 256;

  char* ws = (char*)d_ws;
  size_t o = 0;
  auto alloc = [&](size_t bytes) { size_t r = o; o += (bytes + 511) & ~(size_t)511; return r; };
  size_t cnt_o     = alloc((size_t)N * 4);
  size_t cur_o     = alloc((size_t)N * 4);
  size_t rowptr_o  = alloc((size_t)(N + 1) * 4);
  size_t partial_o = alloc((size_t)NB * 4);
  size_t dinv_o    = alloc((size_t)N * 4);
  size_t csr_o     = alloc((size_t)E * 4);
  size_t h1_o      = alloc((size_t)N * DH * 4);
  size_t g1_o      = alloc((size_t)N * DH * 4);
  size_t h2_o      = h1_o;  // h1 dead after aggregate1 -> reuse for h2

  int*   cnt     = (int*)(ws + cnt_o);
  int*   cursor  = (int*)(ws + cur_o);
  int*   rowptr  = (int*)(ws + rowptr_o);
  int*   partial = (int*)(ws + partial_o);
  float* dinv    = (float*)(ws + dinv_o);
  int*   csr     = (int*)(ws + csr_o);
  float* h1      = (float*)(ws + h1_o);
  float* g1      = (float*)(ws + g1_o);
  float* h2      = (float*)(ws + h2_o);

  hipMemsetAsync(ws + cnt_o, 0, cur_o + (size_t)N * 4 - cnt_o, stream);

  int egrid = (E + 255) / 256;
  count_edges<<<egrid, 256, 0, stream>>>(dst, cnt, E);
  reduce_chunks<<<NB, 256, 0, stream>>>(cnt, partial, N);
  scan_block<<<1, 256, 0, stream>>>(partial, rowptr, NB, N);
  scan_chunks<<<NB, 256, 0, stream>>>(cnt, partial, rowptr, dinv, N);
  fill_csr<<<egrid, 256, 0, stream>>>(src, dst, rowptr, cursor, csr, E);

  gemm_tile<DH, 4><<<(N + 63) / 64, 256, 0, stream>>>(x, W1, dinv, h1, N, DIN);
  aggregate1<<<(N + 3) / 4, 256, 0, stream>>>(h1, rowptr, csr, dinv, b1, g1, N);
  gemm_tile<DOUT, 2><<<(N + 63) / 64, 256, 0, stream>>>(g1, W2, dinv, h2, N, DH);
  aggregate2<<<(N + 3) / 4, 256, 0, stream>>>(h2, rowptr, csr, dinv, b2, out, N);
}

// Round 3
// 409.856 us; speedup vs baseline: 1.5599x; 1.1545x over previous
//
#include <hip/hip_runtime.h>

#define DIN 256
#define DH  128
#define DOUT 64

typedef unsigned int  u32;
typedef unsigned short u16;

__device__ inline u16 f2bf(float f) {            // fp32 -> bf16 round-nearest-even
  u32 u = __float_as_uint(f);
  u32 r = u + 0x7FFF + ((u >> 16) & 1);
  return (u16)(r >> 16);
}
__device__ inline float bf2f_lo(u32 packed) { return __uint_as_float(packed << 16); }
__device__ inline float bf2f_hi(u32 packed) { return __uint_as_float(packed & 0xFFFF0000u); }

// ---------- CSR construction ----------

__global__ __launch_bounds__(256) void count_edges(const int* __restrict__ dst,
                                                   int* __restrict__ cnt, int E) {
  int e = blockIdx.x * 256 + threadIdx.x;
  if (e < E) atomicAdd(&cnt[dst[e]], 1);
}

__global__ __launch_bounds__(256) void reduce_chunks(const int* __restrict__ cnt,
                                                     int* __restrict__ partial, int n) {
  int t = threadIdx.x;
  int g = blockIdx.x * 256 + t;
  int v = (g < n) ? cnt[g] : 0;
  #pragma unroll
  for (int o = 32; o > 0; o >>= 1) v += __shfl_down(v, o, 64);
  __shared__ int sm[4];
  if ((t & 63) == 0) sm[t >> 6] = v;
  __syncthreads();
  if (t == 0) partial[blockIdx.x] = sm[0] + sm[1] + sm[2] + sm[3];
}

__global__ __launch_bounds__(256) void scan_block(int* partial, int* rowptr, int nb, int n) {
  __shared__ int sm[256];
  __shared__ int carry;
  int t = threadIdx.x;
  if (t == 0) carry = 0;
  __syncthreads();
  for (int base = 0; base < nb; base += 256) {
    int g = base + t;
    int v = (g < nb) ? partial[g] : 0;
    sm[t] = v;
    __syncthreads();
    for (int d = 1; d < 256; d <<= 1) {
      int add = (t >= d) ? sm[t - d] : 0;
      __syncthreads();
      sm[t] += add;
      __syncthreads();
    }
    int excl = sm[t] - v + carry;
    if (g < nb) partial[g] = excl;
    __syncthreads();
    if (t == 255) carry = excl + v;
    __syncthreads();
  }
  if (t == 0) rowptr[n] = carry;
}

__global__ __launch_bounds__(256) void scan_chunks(const int* __restrict__ cnt,
    const int* __restrict__ chunkoff, int* __restrict__ rowptr,
    float* __restrict__ dinv, int n) {
  __shared__ int sm[256];
  int t = threadIdx.x, g = blockIdx.x * 256 + t;
  int v = (g < n) ? cnt[g] : 0;
  sm[t] = v;
  __syncthreads();
  for (int d = 1; d < 256; d <<= 1) {
    int add = (t >= d) ? sm[t - d] : 0;
    __syncthreads();
    sm[t] += add;
    __syncthreads();
  }
  if (g < n) {
    rowptr[g] = sm[t] - v + chunkoff[blockIdx.x];
    dinv[g] = rsqrtf((float)(v + 1));       // +1 self-loop
  }
}

__global__ __launch_bounds__(256) void fill_csr(const int* __restrict__ src,
    const int* __restrict__ dst, const int* __restrict__ rowptr,
    int* __restrict__ cursor, int* __restrict__ csr, int E) {
  int e = blockIdx.x * 256 + threadIdx.x;
  if (e < E) {
    int d = dst[e];
    int p = rowptr[d] + atomicAdd(&cursor[d], 1);
    csr[p] = src[e];
  }
}

// ---------- dense transform (fp32 accumulate, LDS-tiled) ----------
// Epilogue: scale row by dinv[row], round to bf16, store packed.

template<int BN, int TN>
__global__ __launch_bounds__(256) void gemm_tile(const float* __restrict__ A,
    const float* __restrict__ W, const float* __restrict__ dinv,
    u16* __restrict__ C, int M, int K) {
  const int tid = threadIdx.x;
  const int tx = tid & 31;
  const int ty = tid >> 5;
  const int rowBase = blockIdx.x * 64;
  __shared__ float xs[64][16];
  __shared__ float wsm[16][BN];
  float acc[8][TN];
  #pragma unroll
  for (int r = 0; r < 8; ++r)
    #pragma unroll
    for (int j = 0; j < TN; ++j) acc[r][j] = 0.f;

  for (int kt = 0; kt < K; kt += 16) {
    {
      int r = tid >> 2, kq = tid & 3;
      int grow = rowBase + r;
      float4 v = make_float4(0.f, 0.f, 0.f, 0.f);
      if (grow < M) v = *(const float4*)&A[(size_t)grow * K + kt + kq * 4];
      *(float4*)&xs[r][kq * 4] = v;
    }
    #pragma unroll
    for (int i = 0; i < BN / 64; ++i) {
      int idx = (tid + i * 256) * 4;
      int kk = idx / BN, c = idx % BN;
      *(float4*)&wsm[kk][c] = *(const float4*)&W[(size_t)(kt + kk) * BN + c];
    }
    __syncthreads();
    #pragma unroll
    for (int kk = 0; kk < 16; ++kk) {
      float a[8];
      #pragma unroll
      for (int r = 0; r < 8; ++r) a[r] = xs[ty * 8 + r][kk];
      float b[TN];
      if (TN == 4) {
        float4 bv = *(float4*)&wsm[kk][tx * 4];
        b[0] = bv.x; b[1] = bv.y; b[2] = bv.z; b[3] = bv.w;
      } else {
        float2 bv = *(float2*)&wsm[kk][tx * 2];
        b[0] = bv.x; b[1] = bv.y;
      }
      #pragma unroll
      for (int r = 0; r < 8; ++r)
        #pragma unroll
        for (int j = 0; j < TN; ++j) acc[r][j] = fmaf(a[r], b[j], acc[r][j]);
    }
    __syncthreads();
  }
  #pragma unroll
  for (int r = 0; r < 8; ++r) {
    int row = rowBase + ty * 8 + r;
    if (row < M) {
      float s = dinv[row];                   // h'[i] = dinv[i] * (A@W)[i], bf16
      if (TN == 4) {
        u32 lo = (u32)f2bf(acc[r][0] * s) | ((u32)f2bf(acc[r][1] * s) << 16);
        u32 hi = (u32)f2bf(acc[r][2] * s) | ((u32)f2bf(acc[r][3] * s) << 16);
        uint2 pv; pv.x = lo; pv.y = hi;
        *(uint2*)&C[(size_t)row * BN + tx * 4] = pv;
      } else {
        u32 lo = (u32)f2bf(acc[r][0] * s) | ((u32)f2bf(acc[r][1] * s) << 16);
        *(u32*)&C[(size_t)row * BN + tx * 2] = lo;
      }
    }
  }
}

// ---------- pull aggregation: one wave per node, 8-deep gather, bf16 rows ----------

__global__ __launch_bounds__(256) void aggregate1(const u16* __restrict__ h,
    const int* __restrict__ rowptr, const int* __restrict__ csr,
    const float* __restrict__ dinv, const float* __restrict__ bias,
    float* __restrict__ out, int n) {
  int lane = threadIdx.x & 63;
  int node = blockIdx.x * 4 + (threadIdx.x >> 6);
  if (node >= n) return;
  node = __builtin_amdgcn_readfirstlane(node);
  float di = dinv[node];
  int c0 = lane * 2;
  u32 w0 = *(const u32*)&h[(size_t)node * DH + c0];   // self-loop (pre-scaled)
  float ax = bf2f_lo(w0), ay = bf2f_hi(w0);
  int p = rowptr[node], pe = rowptr[node + 1];
  for (; p + 8 <= pe; p += 8) {
    int s[8];
    #pragma unroll
    for (int j = 0; j < 8; ++j) s[j] = csr[p + j];
    #pragma unroll
    for (int j = 0; j < 8; ++j) {
      u32 w = *(const u32*)&h[(size_t)s[j] * DH + c0];
      ax += bf2f_lo(w); ay += bf2f_hi(w);
    }
  }
  for (; p < pe; ++p) {
    u32 w = *(const u32*)&h[(size_t)csr[p] * DH + c0];
    ax += bf2f_lo(w); ay += bf2f_hi(w);
  }
  ax = fmaxf(fmaf(ax, di, bias[c0]), 0.f);
  ay = fmaxf(fmaf(ay, di, bias[c0 + 1]), 0.f);
  *(float2*)&out[(size_t)node * DH + c0] = make_float2(ax, ay);
}

__global__ __launch_bounds__(256) void aggregate2(const u16* __restrict__ h,
    const int* __restrict__ rowptr, const int* __restrict__ csr,
    const float* __restrict__ dinv, const float* __restrict__ bias,
    float* __restrict__ out, int n) {
  int lane = threadIdx.x & 63;
  int node = blockIdx.x * 4 + (threadIdx.x >> 6);
  if (node >= n) return;
  node = __builtin_amdgcn_readfirstlane(node);
  float di = dinv[node];
  float a = __uint_as_float((u32)h[(size_t)node * DOUT + lane] << 16);
  int p = rowptr[node], pe = rowptr[node + 1];
  for (; p + 8 <= pe; p += 8) {
    int s[8];
    #pragma unroll
    for (int j = 0; j < 8; ++j) s[j] = csr[p + j];
    #pragma unroll
    for (int j = 0; j < 8; ++j)
      a += __uint_as_float((u32)h[(size_t)s[j] * DOUT + lane] << 16);
  }
  for (; p < pe; ++p)
    a += __uint_as_float((u32)h[(size_t)csr[p] * DOUT + lane] << 16);
  out[(size_t)node * DOUT + lane] = fmaf(a, di, bias[lane]);
}

// ---------- launch ----------

extern "C" void kernel_launch(void* const* d_in, const int* in_sizes, int n_in,
                              void* d_out, int out_size, void* d_ws, size_t ws_size,
                              hipStream_t stream) {
  const float* x  = (const float*)d_in[0];
  const int*   ei = (const int*)d_in[1];
  const float* W1 = (const float*)d_in[2];
  const float* b1 = (const float*)d_in[3];
  const float* W2 = (const float*)d_in[4];
  const float* b2 = (const float*)d_in[5];
  float* out = (float*)d_out;

  const int N = in_sizes[0] / DIN;   // 50000
  const int E = in_sizes[1] / 2;     // 1600000
  const int* src = ei;
  const int* dst = ei + E;
  const int NB = (N + 255) / 256;

  char* ws = (char*)d_ws;
  size_t o = 0;
  auto alloc = [&](size_t bytes) { size_t r = o; o += (bytes + 511) & ~(size_t)511; return r; };
  size_t cnt_o     = alloc((size_t)N * 4);
  size_t cur_o     = alloc((size_t)N * 4);
  size_t rowptr_o  = alloc((size_t)(N + 1) * 4);
  size_t partial_o = alloc((size_t)NB * 4);
  size_t dinv_o    = alloc((size_t)N * 4);
  size_t csr_o     = alloc((size_t)E * 4);
  size_t h1_o      = alloc((size_t)N * DH * 2);   // bf16
  size_t g1_o      = alloc((size_t)N * DH * 4);   // fp32 (GEMM2 input)
  size_t h2_o      = h1_o;  // h1 dead after aggregate1 -> reuse for h2 (bf16)

  int*   cnt     = (int*)(ws + cnt_o);
  int*   cursor  = (int*)(ws + cur_o);
  int*   rowptr  = (int*)(ws + rowptr_o);
  int*   partial = (int*)(ws + partial_o);
  float* dinv    = (float*)(ws + dinv_o);
  int*   csr     = (int*)(ws + csr_o);
  u16*   h1      = (u16*)(ws + h1_o);
  float* g1      = (float*)(ws + g1_o);
  u16*   h2      = (u16*)(ws + h2_o);

  hipMemsetAsync(ws + cnt_o, 0, cur_o + (size_t)N * 4 - cnt_o, stream);

  int egrid = (E + 255) / 256;
  count_edges<<<egrid, 256, 0, stream>>>(dst, cnt, E);
  reduce_chunks<<<NB, 256, 0, stream>>>(cnt, partial, N);
  scan_block<<<1, 256, 0, stream>>>(partial, rowptr, NB, N);
  scan_chunks<<<NB, 256, 0, stream>>>(cnt, partial, rowptr, dinv, N);
  fill_csr<<<egrid, 256, 0, stream>>>(src, dst, rowptr, cursor, csr, E);

  gemm_tile<DH, 4><<<(N + 63) / 64, 256, 0, stream>>>(x, W1, dinv, h1, N, DIN);
  aggregate1<<<(N + 3) / 4, 256, 0, stream>>>(h1, rowptr, csr, dinv, b1, g1, N);
  gemm_tile<DOUT, 2><<<(N + 63) / 64, 256, 0, stream>>>(g1, W2, dinv, h2, N, DH);
  aggregate2<<<(N + 3) / 4, 256, 0, stream>>>(h2, rowptr, csr, dinv, b2, out, N);
}

// Round 4
// 325.000 us; speedup vs baseline: 1.9672x; 1.2611x over previous
//
#include <hip/hip_runtime.h>

#define DIN 256
#define DH  128
#define DOUT 64
#define MAXBUK 800   // >= ceil(N/64); N=50000 -> 782

typedef unsigned int  u32;
typedef unsigned short u16;

__device__ inline u16 f2bf(float f) {            // fp32 -> bf16 round-nearest-even
  u32 u = __float_as_uint(f);
  u32 r = u + 0x7FFF + ((u >> 16) & 1);
  return (u16)(r >> 16);
}
__device__ inline float bf2f_lo(u32 packed) { return __uint_as_float(packed << 16); }
__device__ inline float bf2f_hi(u32 packed) { return __uint_as_float(packed & 0xFFFF0000u); }

// ---------- bucketed CSR construction ----------
// bucket b = dst >> 6  (64 nodes per bucket)

__global__ __launch_bounds__(256) void bucket_count(const int* __restrict__ dst,
    int* __restrict__ bb, int E, int nbuk) {
  __shared__ int h[MAXBUK];
  int tid = threadIdx.x;
  for (int i = tid; i < nbuk; i += 256) h[i] = 0;
  __syncthreads();
  int step = gridDim.x * 256;
  for (int e = blockIdx.x * 256 + tid; e < E; e += step)
    atomicAdd(&h[dst[e] >> 6], 1);
  __syncthreads();
  for (int i = tid; i < nbuk; i += 256)
    if (h[i]) atomicAdd(&bb[i], h[i]);
}

// generic one-block exclusive scan (also used for node rowptr chunk offsets)
__global__ __launch_bounds__(256) void scan_block(int* partial, int* total_out, int nb, int n) {
  __shared__ int sm[256];
  __shared__ int carry;
  int t = threadIdx.x;
  if (t == 0) carry = 0;
  __syncthreads();
  for (int base = 0; base < nb; base += 256) {
    int g = base + t;
    int v = (g < nb) ? partial[g] : 0;
    sm[t] = v;
    __syncthreads();
    for (int d = 1; d < 256; d <<= 1) {
      int add = (t >= d) ? sm[t - d] : 0;
      __syncthreads();
      sm[t] += add;
      __syncthreads();
    }
    int excl = sm[t] - v + carry;
    if (g < nb) partial[g] = excl;
    __syncthreads();
    if (t == 255) carry = excl + v;
    __syncthreads();
  }
  if (t == 0) total_out[n] = carry;
}

// scatter (src,dst) pairs into bucket-contiguous ebuf; block-level reservations
__global__ __launch_bounds__(256) void bucket_scatter(const int* __restrict__ src,
    const int* __restrict__ dst, const int* __restrict__ bb, int* __restrict__ cur,
    uint2* __restrict__ ebuf, int E, int nbuk) {
  __shared__ int h[MAXBUK];
  int tid = threadIdx.x;
  for (int i = tid; i < nbuk; i += 256) h[i] = 0;
  __syncthreads();
  int step = gridDim.x * 256;
  for (int e = blockIdx.x * 256 + tid; e < E; e += step)
    atomicAdd(&h[dst[e] >> 6], 1);
  __syncthreads();
  for (int i = tid; i < nbuk; i += 256) {
    int c = h[i];
    if (c) h[i] = bb[i] + atomicAdd(&cur[i], c);   // reserve contiguous chunk
  }
  __syncthreads();
  for (int e = blockIdx.x * 256 + tid; e < E; e += step) {
    int d = dst[e];
    int r = atomicAdd(&h[d >> 6], 1);
    ebuf[r] = make_uint2((u32)src[e], (u32)d);
  }
}

// per-bucket node degree (dense write, no global atomics)
__global__ __launch_bounds__(256) void bucket_node_count(const uint2* __restrict__ ebuf,
    const int* __restrict__ bb, int* __restrict__ cnt, int N) {
  __shared__ int c[64];
  int b = blockIdx.x, tid = threadIdx.x;
  if (tid < 64) c[tid] = 0;
  __syncthreads();
  int e0 = bb[b], e1 = bb[b + 1];
  for (int e = e0 + tid; e < e1; e += 256)
    atomicAdd(&c[ebuf[e].y & 63], 1);
  __syncthreads();
  int node = b * 64 + tid;
  if (tid < 64 && node < N) cnt[node] = c[tid];
}

__global__ __launch_bounds__(256) void scan_chunks(const int* __restrict__ cnt,
    const int* __restrict__ chunkoff, int* __restrict__ rowptr,
    float* __restrict__ dinv, int n) {
  __shared__ int sm[256];
  int t = threadIdx.x, g = blockIdx.x * 256 + t;
  int v = (g < n) ? cnt[g] : 0;
  sm[t] = v;
  __syncthreads();
  for (int d = 1; d < 256; d <<= 1) {
    int add = (t >= d) ? sm[t - d] : 0;
    __syncthreads();
    sm[t] += add;
    __syncthreads();
  }
  if (g < n) {
    rowptr[g] = sm[t] - v + chunkoff[blockIdx.x];
    dinv[g] = rsqrtf((float)(v + 1));       // +1 self-loop
  }
}

__global__ __launch_bounds__(256) void reduce_chunks(const int* __restrict__ cnt,
                                                     int* __restrict__ partial, int n) {
  int t = threadIdx.x;
  int g = blockIdx.x * 256 + t;
  int v = (g < n) ? cnt[g] : 0;
  #pragma unroll
  for (int o = 32; o > 0; o >>= 1) v += __shfl_down(v, o, 64);
  __shared__ int sm[4];
  if ((t & 63) == 0) sm[t >> 6] = v;
  __syncthreads();
  if (t == 0) partial[blockIdx.x] = sm[0] + sm[1] + sm[2] + sm[3];
}

// per-bucket CSR fill: LDS cursors, csr writes confined to bucket's region
__global__ __launch_bounds__(256) void bucket_fill(const uint2* __restrict__ ebuf,
    const int* __restrict__ bb, const int* __restrict__ rowptr, int* __restrict__ csr) {
  __shared__ int c[64];
  int b = blockIdx.x, tid = threadIdx.x;
  if (tid < 64) c[tid] = 0;
  __syncthreads();
  int e0 = bb[b], e1 = bb[b + 1];
  for (int e = e0 + tid; e < e1; e += 256) {
    uint2 ed = ebuf[e];
    int r = atomicAdd(&c[ed.y & 63], 1);
    csr[rowptr[ed.y] + r] = (int)ed.x;
  }
}

// ---------- dense transform (fp32 accumulate, LDS-tiled), bf16 output ----------

template<int BN, int TN>
__global__ __launch_bounds__(256) void gemm_tile(const float* __restrict__ A,
    const float* __restrict__ W, const float* __restrict__ dinv,
    u16* __restrict__ C, int M, int K) {
  const int tid = threadIdx.x;
  const int tx = tid & 31;
  const int ty = tid >> 5;
  const int rowBase = blockIdx.x * 64;
  __shared__ float xs[64][16];
  __shared__ float wsm[16][BN];
  float acc[8][TN];
  #pragma unroll
  for (int r = 0; r < 8; ++r)
    #pragma unroll
    for (int j = 0; j < TN; ++j) acc[r][j] = 0.f;

  for (int kt = 0; kt < K; kt += 16) {
    {
      int r = tid >> 2, kq = tid & 3;
      int grow = rowBase + r;
      float4 v = make_float4(0.f, 0.f, 0.f, 0.f);
      if (grow < M) v = *(const float4*)&A[(size_t)grow * K + kt + kq * 4];
      *(float4*)&xs[r][kq * 4] = v;
    }
    #pragma unroll
    for (int i = 0; i < BN / 64; ++i) {
      int idx = (tid + i * 256) * 4;
      int kk = idx / BN, c = idx % BN;
      *(float4*)&wsm[kk][c] = *(const float4*)&W[(size_t)(kt + kk) * BN + c];
    }
    __syncthreads();
    #pragma unroll
    for (int kk = 0; kk < 16; ++kk) {
      float a[8];
      #pragma unroll
      for (int r = 0; r < 8; ++r) a[r] = xs[ty * 8 + r][kk];
      float b[TN];
      if (TN == 4) {
        float4 bv = *(float4*)&wsm[kk][tx * 4];
        b[0] = bv.x; b[1] = bv.y; b[2] = bv.z; b[3] = bv.w;
      } else {
        float2 bv = *(float2*)&wsm[kk][tx * 2];
        b[0] = bv.x; b[1] = bv.y;
      }
      #pragma unroll
      for (int r = 0; r < 8; ++r)
        #pragma unroll
        for (int j = 0; j < TN; ++j) acc[r][j] = fmaf(a[r], b[j], acc[r][j]);
    }
    __syncthreads();
  }
  #pragma unroll
  for (int r = 0; r < 8; ++r) {
    int row = rowBase + ty * 8 + r;
    if (row < M) {
      float s = dinv[row];                   // h'[i] = dinv[i] * (A@W)[i], bf16
      if (TN == 4) {
        u32 lo = (u32)f2bf(acc[r][0] * s) | ((u32)f2bf(acc[r][1] * s) << 16);
        u32 hi = (u32)f2bf(acc[r][2] * s) | ((u32)f2bf(acc[r][3] * s) << 16);
        uint2 pv; pv.x = lo; pv.y = hi;
        *(uint2*)&C[(size_t)row * BN + tx * 4] = pv;
      } else {
        u32 lo = (u32)f2bf(acc[r][0] * s) | ((u32)f2bf(acc[r][1] * s) << 16);
        *(u32*)&C[(size_t)row * BN + tx * 2] = lo;
      }
    }
  }
}

// ---------- pull aggregation: one wave per node, 8-deep gather, bf16 rows ----------

__global__ __launch_bounds__(256) void aggregate1(const u16* __restrict__ h,
    const int* __restrict__ rowptr, const int* __restrict__ csr,
    const float* __restrict__ dinv, const float* __restrict__ bias,
    float* __restrict__ out, int n) {
  int lane = threadIdx.x & 63;
  int node = blockIdx.x * 4 + (threadIdx.x >> 6);
  if (node >= n) return;
  node = __builtin_amdgcn_readfirstlane(node);
  float di = dinv[node];
  int c0 = lane * 2;
  u32 w0 = *(const u32*)&h[(size_t)node * DH + c0];   // self-loop (pre-scaled)
  float ax = bf2f_lo(w0), ay = bf2f_hi(w0);
  int p = rowptr[node], pe = rowptr[node + 1];
  for (; p + 8 <= pe; p += 8) {
    int s[8];
    #pragma unroll
    for (int j = 0; j < 8; ++j) s[j] = csr[p + j];
    #pragma unroll
    for (int j = 0; j < 8; ++j) {
      u32 w = *(const u32*)&h[(size_t)s[j] * DH + c0];
      ax += bf2f_lo(w); ay += bf2f_hi(w);
    }
  }
  for (; p < pe; ++p) {
    u32 w = *(const u32*)&h[(size_t)csr[p] * DH + c0];
    ax += bf2f_lo(w); ay += bf2f_hi(w);
  }
  ax = fmaxf(fmaf(ax, di, bias[c0]), 0.f);
  ay = fmaxf(fmaf(ay, di, bias[c0 + 1]), 0.f);
  *(float2*)&out[(size_t)node * DH + c0] = make_float2(ax, ay);
}

__global__ __launch_bounds__(256) void aggregate2(const u16* __restrict__ h,
    const int* __restrict__ rowptr, const int* __restrict__ csr,
    const float* __restrict__ dinv, const float* __restrict__ bias,
    float* __restrict__ out, int n) {
  int lane = threadIdx.x & 63;
  int node = blockIdx.x * 4 + (threadIdx.x >> 6);
  if (node >= n) return;
  node = __builtin_amdgcn_readfirstlane(node);
  float di = dinv[node];
  float a = __uint_as_float((u32)h[(size_t)node * DOUT + lane] << 16);
  int p = rowptr[node], pe = rowptr[node + 1];
  for (; p + 8 <= pe; p += 8) {
    int s[8];
    #pragma unroll
    for (int j = 0; j < 8; ++j) s[j] = csr[p + j];
    #pragma unroll
    for (int j = 0; j < 8; ++j)
      a += __uint_as_float((u32)h[(size_t)s[j] * DOUT + lane] << 16);
  }
  for (; p < pe; ++p)
    a += __uint_as_float((u32)h[(size_t)csr[p] * DOUT + lane] << 16);
  out[(size_t)node * DOUT + lane] = fmaf(a, di, bias[lane]);
}

// ---------- launch ----------

extern "C" void kernel_launch(void* const* d_in, const int* in_sizes, int n_in,
                              void* d_out, int out_size, void* d_ws, size_t ws_size,
                              hipStream_t stream) {
  const float* x  = (const float*)d_in[0];
  const int*   ei = (const int*)d_in[1];
  const float* W1 = (const float*)d_in[2];
  const float* b1 = (const float*)d_in[3];
  const float* W2 = (const float*)d_in[4];
  const float* b2 = (const float*)d_in[5];
  float* out = (float*)d_out;

  const int N = in_sizes[0] / DIN;   // 50000
  const int E = in_sizes[1] / 2;     // 1600000
  const int* src = ei;
  const int* dst = ei + E;
  const int NB = (N + 255) / 256;
  const int nbuk = (N + 63) / 64;    // 782 (<= MAXBUK)

  char* ws = (char*)d_ws;
  size_t o = 0;
  auto alloc = [&](size_t bytes) { size_t r = o; o += (bytes + 511) & ~(size_t)511; return r; };
  size_t bb_o      = alloc((size_t)(2 * nbuk + 1) * 4);  // bb[nbuk+1] then cur[nbuk]
  size_t rowptr_o  = alloc((size_t)(N + 1) * 4);
  size_t partial_o = alloc((size_t)NB * 4);
  size_t dinv_o    = alloc((size_t)N * 4);
  size_t cnt_o     = alloc((size_t)N * 4);
  size_t csr_o     = alloc((size_t)E * 4);
  size_t h1_o      = alloc((size_t)N * DH * 2);   // bf16
  size_t g1_o      = alloc((size_t)N * DH * 4);   // fp32 (GEMM2 input)
  size_t h2_o      = h1_o;   // h1 dead after aggregate1 -> reuse for h2 (bf16)
  size_t ebuf_o    = g1_o;   // ebuf dead before aggregate1 writes g1 -> overlap

  int*   bb      = (int*)(ws + bb_o);
  int*   cur     = bb + (nbuk + 1);
  int*   rowptr  = (int*)(ws + rowptr_o);
  int*   partial = (int*)(ws + partial_o);
  float* dinv    = (float*)(ws + dinv_o);
  int*   cnt     = (int*)(ws + cnt_o);
  int*   csr     = (int*)(ws + csr_o);
  u16*   h1      = (u16*)(ws + h1_o);
  float* g1      = (float*)(ws + g1_o);
  u16*   h2      = (u16*)(ws + h2_o);
  uint2* ebuf    = (uint2*)(ws + ebuf_o);

  hipMemsetAsync(bb, 0, (size_t)(2 * nbuk + 1) * 4, stream);

  bucket_count<<<256, 256, 0, stream>>>(dst, bb, E, nbuk);
  scan_block<<<1, 256, 0, stream>>>(bb, bb, nbuk, nbuk);        // bb -> exclusive bases, bb[nbuk]=E
  bucket_scatter<<<256, 256, 0, stream>>>(src, dst, bb, cur, ebuf, E, nbuk);
  bucket_node_count<<<nbuk, 256, 0, stream>>>(ebuf, bb, cnt, N);
  reduce_chunks<<<NB, 256, 0, stream>>>(cnt, partial, N);
  scan_block<<<1, 256, 0, stream>>>(partial, rowptr, NB, N);
  scan_chunks<<<NB, 256, 0, stream>>>(cnt, partial, rowptr, dinv, N);
  bucket_fill<<<nbuk, 256, 0, stream>>>(ebuf, bb, rowptr, csr);

  gemm_tile<DH, 4><<<(N + 63) / 64, 256, 0, stream>>>(x, W1, dinv, h1, N, DIN);
  aggregate1<<<(N + 3) / 4, 256, 0, stream>>>(h1, rowptr, csr, dinv, b1, g1, N);
  gemm_tile<DOUT, 2><<<(N + 63) / 64, 256, 0, stream>>>(g1, W2, dinv, h2, N, DH);
  aggregate2<<<(N + 3) / 4, 256, 0, stream>>>(h2, rowptr, csr, dinv, b2, out, N);
}

// Round 5
// 291.386 us; speedup vs baseline: 2.1942x; 1.1154x over previous
//
#include <hip/hip_runtime.h>

#define DIN 256
#define DH  128
#define DOUT 64
#define MAXBUK 800   // >= ceil(N/64); N=50000 -> 782

typedef unsigned int  u32;
typedef unsigned short u16;
typedef __attribute__((ext_vector_type(8))) short bf16x8;
typedef __attribute__((ext_vector_type(4))) float f32x4;

__device__ inline u16 f2bf(float f) {            // fp32 -> bf16 round-nearest-even
  u32 u = __float_as_uint(f);
  u32 r = u + 0x7FFF + ((u >> 16) & 1);
  return (u16)(r >> 16);
}
__device__ inline float bf2f_lo(u32 packed) { return __uint_as_float(packed << 16); }
__device__ inline float bf2f_hi(u32 packed) { return __uint_as_float(packed & 0xFFFF0000u); }

// ---------- bucketed CSR construction ----------

__global__ __launch_bounds__(256) void bucket_count(const int* __restrict__ dst,
    int* __restrict__ bb, int E, int nbuk) {
  __shared__ int h[MAXBUK];
  int tid = threadIdx.x;
  for (int i = tid; i < nbuk; i += 256) h[i] = 0;
  __syncthreads();
  int step = gridDim.x * 256;
  for (int e = blockIdx.x * 256 + tid; e < E; e += step)
    atomicAdd(&h[dst[e] >> 6], 1);
  __syncthreads();
  for (int i = tid; i < nbuk; i += 256)
    if (h[i]) atomicAdd(&bb[i], h[i]);
}

__global__ __launch_bounds__(256) void scan_block(int* partial, int* total_out, int nb, int n) {
  __shared__ int sm[256];
  __shared__ int carry;
  int t = threadIdx.x;
  if (t == 0) carry = 0;
  __syncthreads();
  for (int base = 0; base < nb; base += 256) {
    int g = base + t;
    int v = (g < nb) ? partial[g] : 0;
    sm[t] = v;
    __syncthreads();
    for (int d = 1; d < 256; d <<= 1) {
      int add = (t >= d) ? sm[t - d] : 0;
      __syncthreads();
      sm[t] += add;
      __syncthreads();
    }
    int excl = sm[t] - v + carry;
    if (g < nb) partial[g] = excl;
    __syncthreads();
    if (t == 255) carry = excl + v;
    __syncthreads();
  }
  if (t == 0) total_out[n] = carry;
}

__global__ __launch_bounds__(256) void bucket_scatter(const int* __restrict__ src,
    const int* __restrict__ dst, const int* __restrict__ bb, int* __restrict__ cur,
    uint2* __restrict__ ebuf, int E, int nbuk) {
  __shared__ int h[MAXBUK];
  int tid = threadIdx.x;
  for (int i = tid; i < nbuk; i += 256) h[i] = 0;
  __syncthreads();
  int step = gridDim.x * 256;
  for (int e = blockIdx.x * 256 + tid; e < E; e += step)
    atomicAdd(&h[dst[e] >> 6], 1);
  __syncthreads();
  for (int i = tid; i < nbuk; i += 256) {
    int c = h[i];
    if (c) h[i] = bb[i] + atomicAdd(&cur[i], c);
  }
  __syncthreads();
  for (int e = blockIdx.x * 256 + tid; e < E; e += step) {
    int d = dst[e];
    int r = atomicAdd(&h[d >> 6], 1);
    ebuf[r] = make_uint2((u32)src[e], (u32)d);
  }
}

__global__ __launch_bounds__(256) void bucket_node_count(const uint2* __restrict__ ebuf,
    const int* __restrict__ bb, int* __restrict__ cnt, int N) {
  __shared__ int c[64];
  int b = blockIdx.x, tid = threadIdx.x;
  if (tid < 64) c[tid] = 0;
  __syncthreads();
  int e0 = bb[b], e1 = bb[b + 1];
  for (int e = e0 + tid; e < e1; e += 256)
    atomicAdd(&c[ebuf[e].y & 63], 1);
  __syncthreads();
  int node = b * 64 + tid;
  if (tid < 64 && node < N) cnt[node] = c[tid];
}

__global__ __launch_bounds__(256) void scan_chunks(const int* __restrict__ cnt,
    const int* __restrict__ chunkoff, int* __restrict__ rowptr,
    float* __restrict__ dinv, int n) {
  __shared__ int sm[256];
  int t = threadIdx.x, g = blockIdx.x * 256 + t;
  int v = (g < n) ? cnt[g] : 0;
  sm[t] = v;
  __syncthreads();
  for (int d = 1; d < 256; d <<= 1) {
    int add = (t >= d) ? sm[t - d] : 0;
    __syncthreads();
    sm[t] += add;
    __syncthreads();
  }
  if (g < n) {
    rowptr[g] = sm[t] - v + chunkoff[blockIdx.x];
    dinv[g] = rsqrtf((float)(v + 1));       // +1 self-loop
  }
}

__global__ __launch_bounds__(256) void reduce_chunks(const int* __restrict__ cnt,
                                                     int* __restrict__ partial, int n) {
  int t = threadIdx.x;
  int g = blockIdx.x * 256 + t;
  int v = (g < n) ? cnt[g] : 0;
  #pragma unroll
  for (int o = 32; o > 0; o >>= 1) v += __shfl_down(v, o, 64);
  __shared__ int sm[4];
  if ((t & 63) == 0) sm[t >> 6] = v;
  __syncthreads();
  if (t == 0) partial[blockIdx.x] = sm[0] + sm[1] + sm[2] + sm[3];
}

__global__ __launch_bounds__(256) void bucket_fill(const uint2* __restrict__ ebuf,
    const int* __restrict__ bb, const int* __restrict__ rowptr, int* __restrict__ csr) {
  __shared__ int c[64];
  int b = blockIdx.x, tid = threadIdx.x;
  if (tid < 64) c[tid] = 0;
  __syncthreads();
  int e0 = bb[b], e1 = bb[b + 1];
  for (int e = e0 + tid; e < e1; e += 256) {
    uint2 ed = ebuf[e];
    int r = atomicAdd(&c[ed.y & 63], 1);
    csr[rowptr[ed.y] + r] = (int)ed.x;
  }
}

// ---------- W1 -> bf16 transposed [DH][DIN] (one-shot, tiny) ----------

__global__ __launch_bounds__(256) void w1_to_bf16T(const float* __restrict__ W1,
                                                   u16* __restrict__ w1t) {
  int t = blockIdx.x * 256 + threadIdx.x;   // 32768 threads
  int n = t >> 8, k = t & 255;
  w1t[t] = f2bf(W1[k * DH + n]);            // w1t[n*256+k]
}

// ---------- GEMM1: bf16 MFMA, BM=64 BN=128 BK=64, epilogue dinv*bf16 ----------
// A staged fp32->bf16; B from pre-transposed w1t. LDS rows padded to 72 bf16
// (144 B) -> frag reads alias only 2-way (free).

__global__ __launch_bounds__(256) void gemm1_mfma(const float* __restrict__ x,
    const u16* __restrict__ w1t, const float* __restrict__ dinv,
    u16* __restrict__ h1, int M) {
  __shared__ u16 As[64][72];
  __shared__ u16 Bs[128][72];
  const int tid = threadIdx.x;
  const int lane = tid & 63, w = tid >> 6;
  const int row16 = lane & 15, quad = lane >> 4;
  const int rowBase = blockIdx.x * 64;
  f32x4 acc[8];
  #pragma unroll
  for (int nt = 0; nt < 8; ++nt) acc[nt] = (f32x4)(0.f);

  for (int kt = 0; kt < DIN; kt += 64) {
    {  // stage A: 64 rows x 64 k, fp32 -> bf16
      int r = tid >> 2, kq = tid & 3;
      int grow = rowBase + r;
      #pragma unroll
      for (int i = 0; i < 4; ++i) {
        float4 v = make_float4(0.f, 0.f, 0.f, 0.f);
        if (grow < M) v = *(const float4*)&x[(size_t)grow * DIN + kt + kq * 16 + i * 4];
        u32 lo = (u32)f2bf(v.x) | ((u32)f2bf(v.y) << 16);
        u32 hi = (u32)f2bf(v.z) | ((u32)f2bf(v.w) << 16);
        *(uint2*)&As[r][kq * 16 + i * 4] = make_uint2(lo, hi);
      }
    }
    {  // stage B: 128 n-rows x 64 k, bf16 dense copy
      int n = tid >> 1, half = tid & 1;
      const uint4* s = (const uint4*)&w1t[n * DIN + kt + half * 32];
      uint4* d = (uint4*)&Bs[n][half * 32];
      d[0] = s[0]; d[1] = s[1]; d[2] = s[2]; d[3] = s[3];
    }
    __syncthreads();
    #pragma unroll
    for (int ks = 0; ks < 64; ks += 32) {
      bf16x8 a = *(bf16x8*)&As[w * 16 + row16][ks + quad * 8];
      #pragma unroll
      for (int nt = 0; nt < 8; ++nt) {
        bf16x8 b = *(bf16x8*)&Bs[nt * 16 + row16][ks + quad * 8];
        acc[nt] = __builtin_amdgcn_mfma_f32_16x16x32_bf16(a, b, acc[nt], 0, 0, 0);
      }
    }
    __syncthreads();
  }
  // epilogue: D[m=quad*4+reg][n=nt*16+row16]  (m89-verified C/D layout)
  #pragma unroll
  for (int reg = 0; reg < 4; ++reg) {
    int row = rowBase + w * 16 + quad * 4 + reg;
    if (row < M) {
      float s = dinv[row];
      #pragma unroll
      for (int nt = 0; nt < 8; ++nt)
        h1[(size_t)row * DH + nt * 16 + row16] = f2bf(acc[nt][reg] * s);
    }
  }
}

// ---------- GEMM2 (fp32 vector, unchanged), bf16 output ----------

template<int BN, int TN>
__global__ __launch_bounds__(256) void gemm_tile(const float* __restrict__ A,
    const float* __restrict__ W, const float* __restrict__ dinv,
    u16* __restrict__ C, int M, int K) {
  const int tid = threadIdx.x;
  const int tx = tid & 31;
  const int ty = tid >> 5;
  const int rowBase = blockIdx.x * 64;
  __shared__ float xs[64][16];
  __shared__ float wsm[16][BN];
  float acc[8][TN];
  #pragma unroll
  for (int r = 0; r < 8; ++r)
    #pragma unroll
    for (int j = 0; j < TN; ++j) acc[r][j] = 0.f;

  for (int kt = 0; kt < K; kt += 16) {
    {
      int r = tid >> 2, kq = tid & 3;
      int grow = rowBase + r;
      float4 v = make_float4(0.f, 0.f, 0.f, 0.f);
      if (grow < M) v = *(const float4*)&A[(size_t)grow * K + kt + kq * 4];
      *(float4*)&xs[r][kq * 4] = v;
    }
    #pragma unroll
    for (int i = 0; i < BN / 64; ++i) {
      int idx = (tid + i * 256) * 4;
      int kk = idx / BN, c = idx % BN;
      *(float4*)&wsm[kk][c] = *(const float4*)&W[(size_t)(kt + kk) * BN + c];
    }
    __syncthreads();
    #pragma unroll
    for (int kk = 0; kk < 16; ++kk) {
      float a[8];
      #pragma unroll
      for (int r = 0; r < 8; ++r) a[r] = xs[ty * 8 + r][kk];
      float b[TN];
      if (TN == 4) {
        float4 bv = *(float4*)&wsm[kk][tx * 4];
        b[0] = bv.x; b[1] = bv.y; b[2] = bv.z; b[3] = bv.w;
      } else {
        float2 bv = *(float2*)&wsm[kk][tx * 2];
        b[0] = bv.x; b[1] = bv.y;
      }
      #pragma unroll
      for (int r = 0; r < 8; ++r)
        #pragma unroll
        for (int j = 0; j < TN; ++j) acc[r][j] = fmaf(a[r], b[j], acc[r][j]);
    }
    __syncthreads();
  }
  #pragma unroll
  for (int r = 0; r < 8; ++r) {
    int row = rowBase + ty * 8 + r;
    if (row < M) {
      float s = dinv[row];
      if (TN == 4) {
        u32 lo = (u32)f2bf(acc[r][0] * s) | ((u32)f2bf(acc[r][1] * s) << 16);
        u32 hi = (u32)f2bf(acc[r][2] * s) | ((u32)f2bf(acc[r][3] * s) << 16);
        uint2 pv; pv.x = lo; pv.y = hi;
        *(uint2*)&C[(size_t)row * BN + tx * 4] = pv;
      } else {
        u32 lo = (u32)f2bf(acc[r][0] * s) | ((u32)f2bf(acc[r][1] * s) << 16);
        *(u32*)&C[(size_t)row * BN + tx * 2] = lo;
      }
    }
  }
}

// ---------- pull aggregation: one wave per node, 8-deep gather, bf16 rows ----------

__global__ __launch_bounds__(256) void aggregate1(const u16* __restrict__ h,
    const int* __restrict__ rowptr, const int* __restrict__ csr,
    const float* __restrict__ dinv, const float* __restrict__ bias,
    float* __restrict__ out, int n) {
  int lane = threadIdx.x & 63;
  int node = blockIdx.x * 4 + (threadIdx.x >> 6);
  if (node >= n) return;
  node = __builtin_amdgcn_readfirstlane(node);
  float di = dinv[node];
  int c0 = lane * 2;
  u32 w0 = *(const u32*)&h[(size_t)node * DH + c0];
  float ax = bf2f_lo(w0), ay = bf2f_hi(w0);
  int p = rowptr[node], pe = rowptr[node + 1];
  for (; p + 8 <= pe; p += 8) {
    int s[8];
    #pragma unroll
    for (int j = 0; j < 8; ++j) s[j] = csr[p + j];
    #pragma unroll
    for (int j = 0; j < 8; ++j) {
      u32 w = *(const u32*)&h[(size_t)s[j] * DH + c0];
      ax += bf2f_lo(w); ay += bf2f_hi(w);
    }
  }
  for (; p < pe; ++p) {
    u32 w = *(const u32*)&h[(size_t)csr[p] * DH + c0];
    ax += bf2f_lo(w); ay += bf2f_hi(w);
  }
  ax = fmaxf(fmaf(ax, di, bias[c0]), 0.f);
  ay = fmaxf(fmaf(ay, di, bias[c0 + 1]), 0.f);
  *(float2*)&out[(size_t)node * DH + c0] = make_float2(ax, ay);
}

__global__ __launch_bounds__(256) void aggregate2(const u16* __restrict__ h,
    const int* __restrict__ rowptr, const int* __restrict__ csr,
    const float* __restrict__ dinv, const float* __restrict__ bias,
    float* __restrict__ out, int n) {
  int lane = threadIdx.x & 63;
  int node = blockIdx.x * 4 + (threadIdx.x >> 6);
  if (node >= n) return;
  node = __builtin_amdgcn_readfirstlane(node);
  float di = dinv[node];
  float a = __uint_as_float((u32)h[(size_t)node * DOUT + lane] << 16);
  int p = rowptr[node], pe = rowptr[node + 1];
  for (; p + 8 <= pe; p += 8) {
    int s[8];
    #pragma unroll
    for (int j = 0; j < 8; ++j) s[j] = csr[p + j];
    #pragma unroll
    for (int j = 0; j < 8; ++j)
      a += __uint_as_float((u32)h[(size_t)s[j] * DOUT + lane] << 16);
  }
  for (; p < pe; ++p)
    a += __uint_as_float((u32)h[(size_t)csr[p] * DOUT + lane] << 16);
  out[(size_t)node * DOUT + lane] = fmaf(a, di, bias[lane]);
}

// ---------- launch ----------

extern "C" void kernel_launch(void* const* d_in, const int* in_sizes, int n_in,
                              void* d_out, int out_size, void* d_ws, size_t ws_size,
                              hipStream_t stream) {
  const float* x  = (const float*)d_in[0];
  const int*   ei = (const int*)d_in[1];
  const float* W1 = (const float*)d_in[2];
  const float* b1 = (const float*)d_in[3];
  const float* W2 = (const float*)d_in[4];
  const float* b2 = (const float*)d_in[5];
  float* out = (float*)d_out;

  const int N = in_sizes[0] / DIN;   // 50000
  const int E = in_sizes[1] / 2;     // 1600000
  const int* src = ei;
  const int* dst = ei + E;
  const int NB = (N + 255) / 256;
  const int nbuk = (N + 63) / 64;    // 782 (<= MAXBUK)

  char* ws = (char*)d_ws;
  size_t o = 0;
  auto alloc = [&](size_t bytes) { size_t r = o; o += (bytes + 511) & ~(size_t)511; return r; };
  size_t bb_o      = alloc((size_t)(2 * nbuk + 1) * 4);
  size_t rowptr_o  = alloc((size_t)(N + 1) * 4);
  size_t partial_o = alloc((size_t)NB * 4);
  size_t dinv_o    = alloc((size_t)N * 4);
  size_t cnt_o     = alloc((size_t)N * 4);
  size_t w1t_o     = alloc((size_t)DH * DIN * 2);
  size_t csr_o     = alloc((size_t)E * 4);
  size_t h1_o      = alloc((size_t)N * DH * 2);   // bf16
  size_t g1_o      = alloc((size_t)N * DH * 4);   // fp32 (GEMM2 input)
  size_t h2_o      = h1_o;   // h1 dead after aggregate1 -> reuse (bf16)
  size_t ebuf_o    = g1_o;   // ebuf dead before aggregate1 writes g1

  int*   bb      = (int*)(ws + bb_o);
  int*   cur     = bb + (nbuk + 1);
  int*   rowptr  = (int*)(ws + rowptr_o);
  int*   partial = (int*)(ws + partial_o);
  float* dinv    = (float*)(ws + dinv_o);
  int*   cnt     = (int*)(ws + cnt_o);
  u16*   w1t     = (u16*)(ws + w1t_o);
  int*   csr     = (int*)(ws + csr_o);
  u16*   h1      = (u16*)(ws + h1_o);
  float* g1      = (float*)(ws + g1_o);
  u16*   h2      = (u16*)(ws + h2_o);
  uint2* ebuf    = (uint2*)(ws + ebuf_o);

  hipMemsetAsync(bb, 0, (size_t)(2 * nbuk + 1) * 4, stream);

  w1_to_bf16T<<<(DH * DIN) / 256, 256, 0, stream>>>(W1, w1t);
  bucket_count<<<256, 256, 0, stream>>>(dst, bb, E, nbuk);
  scan_block<<<1, 256, 0, stream>>>(bb, bb, nbuk, nbuk);
  bucket_scatter<<<256, 256, 0, stream>>>(src, dst, bb, cur, ebuf, E, nbuk);
  bucket_node_count<<<nbuk, 256, 0, stream>>>(ebuf, bb, cnt, N);
  reduce_chunks<<<NB, 256, 0, stream>>>(cnt, partial, N);
  scan_block<<<1, 256, 0, stream>>>(partial, rowptr, NB, N);
  scan_chunks<<<NB, 256, 0, stream>>>(cnt, partial, rowptr, dinv, N);
  bucket_fill<<<nbuk, 256, 0, stream>>>(ebuf, bb, rowptr, csr);

  gemm1_mfma<<<(N + 63) / 64, 256, 0, stream>>>(x, w1t, dinv, h1, N);
  aggregate1<<<(N + 3) / 4, 256, 0, stream>>>(h1, rowptr, csr, dinv, b1, g1, N);
  gemm_tile<DOUT, 2><<<(N + 63) / 64, 256, 0, stream>>>(g1, W2, dinv, h2, N, DH);
  aggregate2<<<(N + 3) / 4, 256, 0, stream>>>(h2, rowptr, csr, dinv, b2, out, N);
}

// Round 6
// 264.089 us; speedup vs baseline: 2.4210x; 1.1034x over previous
//
#include <hip/hip_runtime.h>

#define DIN 256
#define DH  128
#define DOUT 64
#define BSH  7          // bucket = 128 nodes
#define BNODES 128
#define MAXBUK 400      // >= ceil(N/128); N=50000 -> 391
#define NBLK 512        // histogram/scatter grid

typedef unsigned int  u32;
typedef unsigned short u16;
typedef __attribute__((ext_vector_type(8))) short bf16x8;
typedef __attribute__((ext_vector_type(4))) float f32x4;

__device__ inline u16 f2bf(float f) {            // fp32 -> bf16 round-nearest-even
  u32 u = __float_as_uint(f);
  u32 r = u + 0x7FFF + ((u >> 16) & 1);
  return (u16)(r >> 16);
}
__device__ inline float bf2f_lo(u32 packed) { return __uint_as_float(packed << 16); }
__device__ inline float bf2f_hi(u32 packed) { return __uint_as_float(packed & 0xFFFF0000u); }

// ---------- radix-style CSR construction (no global atomics) ----------

// pass 1: per-block histogram -> counts[buk][block]  (bucket-major, dense)
__global__ __launch_bounds__(256) void hist_kernel(const int* __restrict__ dst,
    int* __restrict__ counts, int E, int nbuk) {
  __shared__ int h[MAXBUK];
  int tid = threadIdx.x, b = blockIdx.x;
  for (int i = tid; i < nbuk; i += 256) h[i] = 0;
  __syncthreads();
  int ech = (E + NBLK - 1) / NBLK;
  int e0 = b * ech, e1 = min(E, e0 + ech);
  for (int e = e0 + tid; e < e1; e += 256)
    atomicAdd(&h[dst[e] >> BSH], 1);
  __syncthreads();
  for (int i = tid; i < nbuk; i += 256) counts[(size_t)i * NBLK + b] = h[i];
}

// pass 2: scan each bucket's row over blocks -> exclusive offsets + bucket total
__global__ __launch_bounds__(256) void col_scan(int* __restrict__ counts,
    int* __restrict__ colsum, int nbuk) {
  __shared__ int sm[256];
  __shared__ int carry;
  int buk = blockIdx.x, t = threadIdx.x;
  if (t == 0) carry = 0;
  __syncthreads();
  int* row = counts + (size_t)buk * NBLK;
  for (int base = 0; base < NBLK; base += 256) {
    int v = row[base + t];
    sm[t] = v;
    __syncthreads();
    for (int d = 1; d < 256; d <<= 1) {
      int a = (t >= d) ? sm[t - d] : 0;
      __syncthreads();
      sm[t] += a;
      __syncthreads();
    }
    int excl = sm[t] - v + carry;
    row[base + t] = excl;
    __syncthreads();
    if (t == 255) carry = excl + v;
    __syncthreads();
  }
  if (t == 0) colsum[buk] = carry;
}

// generic one-block exclusive scan (colsum -> bucket bases; chunk offsets)
__global__ __launch_bounds__(256) void scan_block(int* partial, int* total_out, int nb, int n) {
  __shared__ int sm[256];
  __shared__ int carry;
  int t = threadIdx.x;
  if (t == 0) carry = 0;
  __syncthreads();
  for (int base = 0; base < nb; base += 256) {
    int g = base + t;
    int v = (g < nb) ? partial[g] : 0;
    sm[t] = v;
    __syncthreads();
    for (int d = 1; d < 256; d <<= 1) {
      int add = (t >= d) ? sm[t - d] : 0;
      __syncthreads();
      sm[t] += add;
      __syncthreads();
    }
    int excl = sm[t] - v + carry;
    if (g < nb) partial[g] = excl;
    __syncthreads();
    if (t == 255) carry = excl + v;
    __syncthreads();
  }
  if (t == 0) total_out[n] = carry;
}

// pass 3: scatter packed edges; cursors precomputed, LDS atomics only
__global__ __launch_bounds__(256) void scatter_kernel(const int* __restrict__ src,
    const int* __restrict__ dst, const int* __restrict__ counts,
    const int* __restrict__ bb, u32* __restrict__ ebuf, int E, int nbuk) {
  __shared__ int cur[MAXBUK];
  int tid = threadIdx.x, b = blockIdx.x;
  for (int i = tid; i < nbuk; i += 256)
    cur[i] = bb[i] + counts[(size_t)i * NBLK + b];
  __syncthreads();
  int ech = (E + NBLK - 1) / NBLK;
  int e0 = b * ech, e1 = min(E, e0 + ech);
  for (int e = e0 + tid; e < e1; e += 256) {
    int d = dst[e];
    int r = atomicAdd(&cur[d >> BSH], 1);
    ebuf[r] = (u32)src[e] | ((u32)(d & (BNODES - 1)) << 16);   // N < 65536
  }
}

__global__ __launch_bounds__(256) void bucket_node_count(const u32* __restrict__ ebuf,
    const int* __restrict__ bb, int* __restrict__ cnt, int N) {
  __shared__ int c[BNODES];
  int b = blockIdx.x, tid = threadIdx.x;
  if (tid < BNODES) c[tid] = 0;
  __syncthreads();
  int e0 = bb[b], e1 = bb[b + 1];
  for (int e = e0 + tid; e < e1; e += 256)
    atomicAdd(&c[ebuf[e] >> 16], 1);
  __syncthreads();
  int node = b * BNODES + tid;
  if (tid < BNODES && node < N) cnt[node] = c[tid];
}

__global__ __launch_bounds__(256) void reduce_chunks(const int* __restrict__ cnt,
                                                     int* __restrict__ partial, int n) {
  int t = threadIdx.x;
  int g = blockIdx.x * 256 + t;
  int v = (g < n) ? cnt[g] : 0;
  #pragma unroll
  for (int o = 32; o > 0; o >>= 1) v += __shfl_down(v, o, 64);
  __shared__ int sm[4];
  if ((t & 63) == 0) sm[t >> 6] = v;
  __syncthreads();
  if (t == 0) partial[blockIdx.x] = sm[0] + sm[1] + sm[2] + sm[3];
}

__global__ __launch_bounds__(256) void scan_chunks(const int* __restrict__ cnt,
    const int* __restrict__ chunkoff, int* __restrict__ rowptr,
    float* __restrict__ dinv, int n) {
  __shared__ int sm[256];
  int t = threadIdx.x, g = blockIdx.x * 256 + t;
  int v = (g < n) ? cnt[g] : 0;
  sm[t] = v;
  __syncthreads();
  for (int d = 1; d < 256; d <<= 1) {
    int add = (t >= d) ? sm[t - d] : 0;
    __syncthreads();
    sm[t] += add;
    __syncthreads();
  }
  if (g < n) {
    rowptr[g] = sm[t] - v + chunkoff[blockIdx.x];
    dinv[g] = rsqrtf((float)(v + 1));       // +1 self-loop
  }
}

__global__ __launch_bounds__(256) void bucket_fill(const u32* __restrict__ ebuf,
    const int* __restrict__ bb, const int* __restrict__ rowptr, int* __restrict__ csr) {
  __shared__ int c[BNODES];
  int b = blockIdx.x, tid = threadIdx.x;
  if (tid < BNODES) c[tid] = 0;
  __syncthreads();
  int e0 = bb[b], e1 = bb[b + 1];
  for (int e = e0 + tid; e < e1; e += 256) {
    u32 p = ebuf[e];
    int nl = p >> 16;
    int r = atomicAdd(&c[nl], 1);
    csr[rowptr[b * BNODES + nl] + r] = (int)(p & 0xFFFFu);
  }
}

// ---------- W1 -> bf16 transposed [DH][DIN] ----------

__global__ __launch_bounds__(256) void w1_to_bf16T(const float* __restrict__ W1,
                                                   u16* __restrict__ w1t) {
  int t = blockIdx.x * 256 + threadIdx.x;
  int n = t >> 8, k = t & 255;
  w1t[t] = f2bf(W1[k * DH + n]);
}

// ---------- GEMM1: bf16 MFMA, BM=64 BN=128 BK=64, epilogue dinv*bf16 ----------

__global__ __launch_bounds__(256) void gemm1_mfma(const float* __restrict__ x,
    const u16* __restrict__ w1t, const float* __restrict__ dinv,
    u16* __restrict__ h1, int M) {
  __shared__ u16 As[64][72];
  __shared__ u16 Bs[128][72];
  const int tid = threadIdx.x;
  const int lane = tid & 63, w = tid >> 6;
  const int row16 = lane & 15, quad = lane >> 4;
  const int rowBase = blockIdx.x * 64;
  f32x4 acc[8];
  #pragma unroll
  for (int nt = 0; nt < 8; ++nt) acc[nt] = (f32x4)(0.f);

  for (int kt = 0; kt < DIN; kt += 64) {
    {
      int r = tid >> 2, kq = tid & 3;
      int grow = rowBase + r;
      #pragma unroll
      for (int i = 0; i < 4; ++i) {
        float4 v = make_float4(0.f, 0.f, 0.f, 0.f);
        if (grow < M) v = *(const float4*)&x[(size_t)grow * DIN + kt + kq * 16 + i * 4];
        u32 lo = (u32)f2bf(v.x) | ((u32)f2bf(v.y) << 16);
        u32 hi = (u32)f2bf(v.z) | ((u32)f2bf(v.w) << 16);
        *(uint2*)&As[r][kq * 16 + i * 4] = make_uint2(lo, hi);
      }
    }
    {
      int n = tid >> 1, half = tid & 1;
      const uint4* s = (const uint4*)&w1t[n * DIN + kt + half * 32];
      uint4* d = (uint4*)&Bs[n][half * 32];
      d[0] = s[0]; d[1] = s[1]; d[2] = s[2]; d[3] = s[3];
    }
    __syncthreads();
    #pragma unroll
    for (int ks = 0; ks < 64; ks += 32) {
      bf16x8 a = *(bf16x8*)&As[w * 16 + row16][ks + quad * 8];
      #pragma unroll
      for (int nt = 0; nt < 8; ++nt) {
        bf16x8 b = *(bf16x8*)&Bs[nt * 16 + row16][ks + quad * 8];
        acc[nt] = __builtin_amdgcn_mfma_f32_16x16x32_bf16(a, b, acc[nt], 0, 0, 0);
      }
    }
    __syncthreads();
  }
  #pragma unroll
  for (int reg = 0; reg < 4; ++reg) {
    int row = rowBase + w * 16 + quad * 4 + reg;
    if (row < M) {
      float s = dinv[row];
      #pragma unroll
      for (int nt = 0; nt < 8; ++nt)
        h1[(size_t)row * DH + nt * 16 + row16] = f2bf(acc[nt][reg] * s);
    }
  }
}

// ---------- GEMM2 (fp32 vector), bf16 output ----------

template<int BN, int TN>
__global__ __launch_bounds__(256) void gemm_tile(const float* __restrict__ A,
    const float* __restrict__ W, const float* __restrict__ dinv,
    u16* __restrict__ C, int M, int K) {
  const int tid = threadIdx.x;
  const int tx = tid & 31;
  const int ty = tid >> 5;
  const int rowBase = blockIdx.x * 64;
  __shared__ float xs[64][16];
  __shared__ float wsm[16][BN];
  float acc[8][TN];
  #pragma unroll
  for (int r = 0; r < 8; ++r)
    #pragma unroll
    for (int j = 0; j < TN; ++j) acc[r][j] = 0.f;

  for (int kt = 0; kt < K; kt += 16) {
    {
      int r = tid >> 2, kq = tid & 3;
      int grow = rowBase + r;
      float4 v = make_float4(0.f, 0.f, 0.f, 0.f);
      if (grow < M) v = *(const float4*)&A[(size_t)grow * K + kt + kq * 4];
      *(float4*)&xs[r][kq * 4] = v;
    }
    #pragma unroll
    for (int i = 0; i < BN / 64; ++i) {
      int idx = (tid + i * 256) * 4;
      int kk = idx / BN, c = idx % BN;
      *(float4*)&wsm[kk][c] = *(const float4*)&W[(size_t)(kt + kk) * BN + c];
    }
    __syncthreads();
    #pragma unroll
    for (int kk = 0; kk < 16; ++kk) {
      float a[8];
      #pragma unroll
      for (int r = 0; r < 8; ++r) a[r] = xs[ty * 8 + r][kk];
      float b[TN];
      if (TN == 4) {
        float4 bv = *(float4*)&wsm[kk][tx * 4];
        b[0] = bv.x; b[1] = bv.y; b[2] = bv.z; b[3] = bv.w;
      } else {
        float2 bv = *(float2*)&wsm[kk][tx * 2];
        b[0] = bv.x; b[1] = bv.y;
      }
      #pragma unroll
      for (int r = 0; r < 8; ++r)
        #pragma unroll
        for (int j = 0; j < TN; ++j) acc[r][j] = fmaf(a[r], b[j], acc[r][j]);
    }
    __syncthreads();
  }
  #pragma unroll
  for (int r = 0; r < 8; ++r) {
    int row = rowBase + ty * 8 + r;
    if (row < M) {
      float s = dinv[row];
      if (TN == 4) {
        u32 lo = (u32)f2bf(acc[r][0] * s) | ((u32)f2bf(acc[r][1] * s) << 16);
        u32 hi = (u32)f2bf(acc[r][2] * s) | ((u32)f2bf(acc[r][3] * s) << 16);
        uint2 pv; pv.x = lo; pv.y = hi;
        *(uint2*)&C[(size_t)row * BN + tx * 4] = pv;
      } else {
        u32 lo = (u32)f2bf(acc[r][0] * s) | ((u32)f2bf(acc[r][1] * s) << 16);
        *(u32*)&C[(size_t)row * BN + tx * 2] = lo;
      }
    }
  }
}

// ---------- pull aggregation: one wave per node, 16-deep gather, bf16 rows ----------

__global__ __launch_bounds__(256) void aggregate1(const u16* __restrict__ h,
    const int* __restrict__ rowptr, const int* __restrict__ csr,
    const float* __restrict__ dinv, const float* __restrict__ bias,
    float* __restrict__ out, int n) {
  int lane = threadIdx.x & 63;
  int node = blockIdx.x * 4 + (threadIdx.x >> 6);
  if (node >= n) return;
  node = __builtin_amdgcn_readfirstlane(node);
  float di = dinv[node];
  int c0 = lane * 2;
  u32 w0 = *(const u32*)&h[(size_t)node * DH + c0];
  float ax = bf2f_lo(w0), ay = bf2f_hi(w0);
  int p = rowptr[node], pe = rowptr[node + 1];
  for (; p + 16 <= pe; p += 16) {
    int s[16];
    #pragma unroll
    for (int j = 0; j < 16; ++j) s[j] = csr[p + j];
    #pragma unroll
    for (int j = 0; j < 16; ++j) {
      u32 w = *(const u32*)&h[(size_t)s[j] * DH + c0];
      ax += bf2f_lo(w); ay += bf2f_hi(w);
    }
  }
  for (; p + 4 <= pe; p += 4) {
    int s[4];
    #pragma unroll
    for (int j = 0; j < 4; ++j) s[j] = csr[p + j];
    #pragma unroll
    for (int j = 0; j < 4; ++j) {
      u32 w = *(const u32*)&h[(size_t)s[j] * DH + c0];
      ax += bf2f_lo(w); ay += bf2f_hi(w);
    }
  }
  for (; p < pe; ++p) {
    u32 w = *(const u32*)&h[(size_t)csr[p] * DH + c0];
    ax += bf2f_lo(w); ay += bf2f_hi(w);
  }
  ax = fmaxf(fmaf(ax, di, bias[c0]), 0.f);
  ay = fmaxf(fmaf(ay, di, bias[c0 + 1]), 0.f);
  *(float2*)&out[(size_t)node * DH + c0] = make_float2(ax, ay);
}

__global__ __launch_bounds__(256) void aggregate2(const u16* __restrict__ h,
    const int* __restrict__ rowptr, const int* __restrict__ csr,
    const float* __restrict__ dinv, const float* __restrict__ bias,
    float* __restrict__ out, int n) {
  int lane = threadIdx.x & 63;
  int node = blockIdx.x * 4 + (threadIdx.x >> 6);
  if (node >= n) return;
  node = __builtin_amdgcn_readfirstlane(node);
  float di = dinv[node];
  float a = __uint_as_float((u32)h[(size_t)node * DOUT + lane] << 16);
  int p = rowptr[node], pe = rowptr[node + 1];
  for (; p + 16 <= pe; p += 16) {
    int s[16];
    #pragma unroll
    for (int j = 0; j < 16; ++j) s[j] = csr[p + j];
    #pragma unroll
    for (int j = 0; j < 16; ++j)
      a += __uint_as_float((u32)h[(size_t)s[j] * DOUT + lane] << 16);
  }
  for (; p + 4 <= pe; p += 4) {
    int s[4];
    #pragma unroll
    for (int j = 0; j < 4; ++j) s[j] = csr[p + j];
    #pragma unroll
    for (int j = 0; j < 4; ++j)
      a += __uint_as_float((u32)h[(size_t)s[j] * DOUT + lane] << 16);
  }
  for (; p < pe; ++p)
    a += __uint_as_float((u32)h[(size_t)csr[p] * DOUT + lane] << 16);
  out[(size_t)node * DOUT + lane] = fmaf(a, di, bias[lane]);
}

// ---------- launch ----------

extern "C" void kernel_launch(void* const* d_in, const int* in_sizes, int n_in,
                              void* d_out, int out_size, void* d_ws, size_t ws_size,
                              hipStream_t stream) {
  const float* x  = (const float*)d_in[0];
  const int*   ei = (const int*)d_in[1];
  const float* W1 = (const float*)d_in[2];
  const float* b1 = (const float*)d_in[3];
  const float* W2 = (const float*)d_in[4];
  const float* b2 = (const float*)d_in[5];
  float* out = (float*)d_out;

  const int N = in_sizes[0] / DIN;   // 50000
  const int E = in_sizes[1] / 2;     // 1600000
  const int* src = ei;
  const int* dst = ei + E;
  const int NB = (N + 255) / 256;
  const int nbuk = (N + BNODES - 1) / BNODES;   // 391 (<= MAXBUK)

  char* ws = (char*)d_ws;
  size_t o = 0;
  auto alloc = [&](size_t bytes) { size_t r = o; o += (bytes + 511) & ~(size_t)511; return r; };
  size_t colsum_o  = alloc((size_t)(nbuk + 1) * 4);
  size_t counts_o  = alloc((size_t)nbuk * NBLK * 4);
  size_t rowptr_o  = alloc((size_t)(N + 1) * 4);
  size_t partial_o = alloc((size_t)NB * 4);
  size_t dinv_o    = alloc((size_t)N * 4);
  size_t cnt_o     = alloc((size_t)N * 4);
  size_t w1t_o     = alloc((size_t)DH * DIN * 2);
  size_t csr_o     = alloc((size_t)E * 4);
  size_t h1_o      = alloc((size_t)N * DH * 2);   // bf16
  size_t g1_o      = alloc((size_t)N * DH * 4);   // fp32 (GEMM2 input)
  size_t h2_o      = h1_o;   // h1 dead after aggregate1 -> reuse (bf16)
  size_t ebuf_o    = g1_o;   // ebuf dead before aggregate1 writes g1

  int*   colsum  = (int*)(ws + colsum_o);   // becomes bb after scan_block
  int*   counts  = (int*)(ws + counts_o);
  int*   rowptr  = (int*)(ws + rowptr_o);
  int*   partial = (int*)(ws + partial_o);
  float* dinv    = (float*)(ws + dinv_o);
  int*   cnt     = (int*)(ws + cnt_o);
  u16*   w1t     = (u16*)(ws + w1t_o);
  int*   csr     = (int*)(ws + csr_o);
  u16*   h1      = (u16*)(ws + h1_o);
  float* g1      = (float*)(ws + g1_o);
  u16*   h2      = (u16*)(ws + h2_o);
  u32*   ebuf    = (u32*)(ws + ebuf_o);

  w1_to_bf16T<<<(DH * DIN) / 256, 256, 0, stream>>>(W1, w1t);
  hist_kernel<<<NBLK, 256, 0, stream>>>(dst, counts, E, nbuk);
  col_scan<<<nbuk, 256, 0, stream>>>(counts, colsum, nbuk);
  scan_block<<<1, 256, 0, stream>>>(colsum, colsum, nbuk, nbuk);  // colsum -> bb, bb[nbuk]=E
  scatter_kernel<<<NBLK, 256, 0, stream>>>(src, dst, counts, colsum, ebuf, E, nbuk);
  bucket_node_count<<<nbuk, 256, 0, stream>>>(ebuf, colsum, cnt, N);
  reduce_chunks<<<NB, 256, 0, stream>>>(cnt, partial, N);
  scan_block<<<1, 256, 0, stream>>>(partial, rowptr, NB, N);
  scan_chunks<<<NB, 256, 0, stream>>>(cnt, partial, rowptr, dinv, N);
  bucket_fill<<<nbuk, 256, 0, stream>>>(ebuf, colsum, rowptr, csr);

  gemm1_mfma<<<(N + 63) / 64, 256, 0, stream>>>(x, w1t, dinv, h1, N);
  aggregate1<<<(N + 3) / 4, 256, 0, stream>>>(h1, rowptr, csr, dinv, b1, g1, N);
  gemm_tile<DOUT, 2><<<(N + 63) / 64, 256, 0, stream>>>(g1, W2, dinv, h2, N, DH);
  aggregate2<<<(N + 3) / 4, 256, 0, stream>>>(h2, rowptr, csr, dinv, b2, out, N);
}